// Round 14
// baseline (310.496 us; speedup 1.0000x reference)
//
#include <hip/hip_runtime.h>
#include <hip/hip_bf16.h>

typedef unsigned short u16;
typedef unsigned int u32;
typedef unsigned long long u64;
typedef __bf16 bf16x8 __attribute__((ext_vector_type(8)));
typedef float f32x4 __attribute__((ext_vector_type(4)));
typedef u16 u16x4 __attribute__((ext_vector_type(4)));
typedef u16 u16x8 __attribute__((ext_vector_type(8)));

static constexpr int BB = 2, SS = 2048, HIDC = 2048, LATC = 512, NH = 16, HD = 128;
static constexpr int MROWS = BB * SS;  // 4096
static constexpr float NEGV = -1e9f;

__device__ __forceinline__ u16 f2bf(float f) {
  __hip_bfloat16 h = __float2bfloat16(f);
  return __builtin_bit_cast(u16, h);
}
__device__ __forceinline__ float bf2f(u16 u) {
  return __uint_as_float(((u32)u) << 16);
}
__device__ __forceinline__ void load_lds16(const void* g, void* l) {
  __builtin_amdgcn_global_load_lds(
      (const __attribute__((address_space(1))) void*)g,
      (__attribute__((address_space(3))) void*)l, 16, 0, 0);
}

// ---------------- plain GEMM: C[M][N] = A[M][K] @ Bt[N][K]^T ----------------
// MODE 0: C = f32 store; MODE 2: Cb = bf16 store. Batch via blockIdx.z strides.
// NOTE: natural separate dispatches in natural block order are measured-best:
// XCD remap (R9), interleaved merge (R11), concat merge (R12) all regressed.
template <int MODE>
__global__ __launch_bounds__(256, 2) void gemm_bt(
    const u16* __restrict__ A, const u16* __restrict__ Bt,
    float* __restrict__ C, u16* __restrict__ Cb, int M, int N, int K,
    size_t sA, size_t sB, size_t sC) {
  __shared__ u16 As[128 * 64];
  __shared__ u16 Bs[128 * 64];
  const int tid = threadIdx.x;
  const int lane = tid & 63;
  const int wv = tid >> 6;
  const int wr = wv >> 1, wc = wv & 1;
  const int m0 = blockIdx.x * 128, n0 = blockIdx.y * 128;
  A += sA * blockIdx.z;
  Bt += sB * blockIdx.z;
  if constexpr (MODE == 0) C += sC * blockIdx.z;
  if constexpr (MODE == 2) Cb += sC * blockIdx.z;

  f32x4 acc[4][4];
#pragma unroll
  for (int i = 0; i < 4; ++i)
#pragma unroll
    for (int j = 0; j < 4; ++j) acc[i][j] = (f32x4){0.f, 0.f, 0.f, 0.f};

  int srow[4], sgc[4];
#pragma unroll
  for (int j = 0; j < 4; ++j) {
    int e = j * 2048 + tid * 8;
    int row = e >> 6;
    int slot = (e >> 3) & 7;
    srow[j] = row;
    sgc[j] = (slot ^ (row & 7)) * 8;
  }

  for (int k0 = 0; k0 < K; k0 += 64) {
    __syncthreads();
#pragma unroll
    for (int j = 0; j < 4; ++j) {
      const u16* ga = A + (size_t)(m0 + srow[j]) * K + k0 + sgc[j];
      const u16* gb = Bt + (size_t)(n0 + srow[j]) * K + k0 + sgc[j];
      load_lds16(ga, &As[j * 2048 + wv * 512]);
      load_lds16(gb, &Bs[j * 2048 + wv * 512]);
    }
    asm volatile("s_waitcnt vmcnt(0)" ::: "memory");
    __syncthreads();

#pragma unroll
    for (int kk = 0; kk < 2; ++kk) {
      bf16x8 afr[4], bfr[4];
      const int kg = kk * 4 + (lane >> 4);
#pragma unroll
      for (int i = 0; i < 4; ++i) {
        int ar = wr * 64 + i * 16 + (lane & 15);
        afr[i] = *(const bf16x8*)&As[ar * 64 + ((kg ^ (ar & 7)) << 3)];
        int br = wc * 64 + i * 16 + (lane & 15);
        bfr[i] = *(const bf16x8*)&Bs[br * 64 + ((kg ^ (br & 7)) << 3)];
      }
#pragma unroll
      for (int mi = 0; mi < 4; ++mi)
#pragma unroll
        for (int ni = 0; ni < 4; ++ni)
          acc[mi][ni] = __builtin_amdgcn_mfma_f32_16x16x32_bf16(
              afr[mi], bfr[ni], acc[mi][ni], 0, 0, 0);
    }
  }

#pragma unroll
  for (int mi = 0; mi < 4; ++mi) {
#pragma unroll
    for (int ni = 0; ni < 4; ++ni) {
      const int row = m0 + wr * 64 + mi * 16 + (lane >> 4) * 4;
      const int col = n0 + wc * 64 + ni * 16 + (lane & 15);
#pragma unroll
      for (int r = 0; r < 4; ++r) {
        size_t off = (size_t)(row + r) * N + col;
        if constexpr (MODE == 0) C[off] = acc[mi][ni][r];
        if constexpr (MODE == 2) Cb[off] = f2bf(acc[mi][ni][r]);
      }
    }
  }
}

// -------- fused split GEMM: C = Ah@Bh^T + Ah@Bl^T + Al@Bh^T (f32-accurate) --
template <int TN, int MODE>
__global__ __launch_bounds__(256, 2) void gemm_split_bt(
    const u16* __restrict__ Ah, const u16* __restrict__ Al,
    const u16* __restrict__ Bth, const u16* __restrict__ Btl,
    float* __restrict__ C, u16* __restrict__ Ch, u16* __restrict__ Cl,
    int M, int N, int K) {
  constexpr int NI = TN / 32;
  __shared__ u16 Ash[128 * 64];
  __shared__ u16 Asl[128 * 64];
  __shared__ u16 Bsh[TN * 64];
  __shared__ u16 Bsl[TN * 64];
  const int tid = threadIdx.x;
  const int lane = tid & 63;
  const int wv = tid >> 6;
  const int wr = wv >> 1, wc = wv & 1;
  const int l15 = lane & 15, lhi = lane >> 4;
  const int m0 = blockIdx.x * 128, n0 = blockIdx.y * TN;

  f32x4 acc[4][NI];
#pragma unroll
  for (int i = 0; i < 4; ++i)
#pragma unroll
    for (int j = 0; j < NI; ++j) acc[i][j] = (f32x4){0.f, 0.f, 0.f, 0.f};

  int srow[4], sgc[4];
#pragma unroll
  for (int j = 0; j < 4; ++j) {
    int e = j * 2048 + tid * 8;
    int row = e >> 6;
    int slot = (e >> 3) & 7;
    srow[j] = row;
    sgc[j] = (slot ^ (row & 7)) * 8;
  }

  for (int k0 = 0; k0 < K; k0 += 64) {
    __syncthreads();
#pragma unroll
    for (int j = 0; j < 4; ++j) {
      const size_t ao = (size_t)(m0 + srow[j]) * K + k0 + sgc[j];
      load_lds16(Ah + ao, &Ash[j * 2048 + wv * 512]);
      load_lds16(Al + ao, &Asl[j * 2048 + wv * 512]);
    }
#pragma unroll
    for (int j = 0; j < NI; ++j) {
      const size_t bo = (size_t)(n0 + srow[j]) * K + k0 + sgc[j];
      load_lds16(Bth + bo, &Bsh[j * 2048 + wv * 512]);
      load_lds16(Btl + bo, &Bsl[j * 2048 + wv * 512]);
    }
    asm volatile("s_waitcnt vmcnt(0)" ::: "memory");
    __syncthreads();

#pragma unroll
    for (int kk = 0; kk < 2; ++kk) {
      const int kg = kk * 4 + lhi;
      bf16x8 afh[4], afl[4], bfh[NI], bfl[NI];
#pragma unroll
      for (int i = 0; i < 4; ++i) {
        const int ar = wr * 64 + i * 16 + l15;
        const int off = ar * 64 + ((kg ^ (ar & 7)) << 3);
        afh[i] = *(const bf16x8*)&Ash[off];
        afl[i] = *(const bf16x8*)&Asl[off];
      }
#pragma unroll
      for (int i = 0; i < NI; ++i) {
        const int br = wc * (TN / 2) + i * 16 + l15;
        const int off = br * 64 + ((kg ^ (br & 7)) << 3);
        bfh[i] = *(const bf16x8*)&Bsh[off];
        bfl[i] = *(const bf16x8*)&Bsl[off];
      }
#pragma unroll
      for (int mi = 0; mi < 4; ++mi)
#pragma unroll
        for (int ni = 0; ni < NI; ++ni) {
          acc[mi][ni] = __builtin_amdgcn_mfma_f32_16x16x32_bf16(
              afh[mi], bfh[ni], acc[mi][ni], 0, 0, 0);
          acc[mi][ni] = __builtin_amdgcn_mfma_f32_16x16x32_bf16(
              afh[mi], bfl[ni], acc[mi][ni], 0, 0, 0);
          acc[mi][ni] = __builtin_amdgcn_mfma_f32_16x16x32_bf16(
              afl[mi], bfh[ni], acc[mi][ni], 0, 0, 0);
        }
    }
  }

#pragma unroll
  for (int mi = 0; mi < 4; ++mi) {
#pragma unroll
    for (int ni = 0; ni < NI; ++ni) {
      const int row = m0 + wr * 64 + mi * 16 + lhi * 4;
      const int col = n0 + wc * (TN / 2) + ni * 16 + l15;
#pragma unroll
      for (int r = 0; r < 4; ++r) {
        const size_t off = (size_t)(row + r) * N + col;
        const float v = acc[mi][ni][r];
        if constexpr (MODE == 0) C[off] = v;
        if constexpr (MODE == 3) {
          const u16 hh = f2bf(v);
          Ch[off] = hh;
          Cl[off] = f2bf(v - bf2f(hh));
        }
      }
    }
  }
}

// ------------- merged prep: x split + all weight transposes (one dispatch) --
__global__ __launch_bounds__(256) void prep_all(
    const float* __restrict__ x, u16* __restrict__ xh, u16* __restrict__ xl,
    const float* __restrict__ Wq, u16* __restrict__ Wqh, u16* __restrict__ Wql,
    const float* __restrict__ Wdkv, u16* __restrict__ Wdh, u16* __restrict__ Wdl,
    const float* __restrict__ Wuk, u16* __restrict__ Wukh, u16* __restrict__ Wukl,
    const float* __restrict__ Wuv, u16* __restrict__ Wuvt,
    const float* __restrict__ Wo, u16* __restrict__ Wot) {
  const int bx = blockIdx.x, tid = threadIdx.x;
  if (bx < 8192) {
    const size_t i = ((size_t)bx * 256 + tid) * 4;
    f32x4 v = *(const f32x4*)(x + i);
    u16x4 hh, ll;
#pragma unroll
    for (int e = 0; e < 4; ++e) {
      const u16 hi = f2bf(v[e]);
      hh[e] = hi;
      ll[e] = f2bf(v[e] - bf2f(hi));
    }
    *(u16x4*)(xh + i) = hh;
    *(u16x4*)(xl + i) = ll;
    return;
  }
  __shared__ float t[32][33];
  const float* W;
  u16 *Th, *Tl = nullptr;
  int K, N, gx, gy;
  if (bx < 12288) {
    const int q = bx - 8192;
    W = Wq; Th = Wqh; Tl = Wql; K = 2048; N = 2048; gx = q & 63; gy = q >> 6;
  } else if (bx < 13312) {
    const int q = bx - 12288;
    W = Wdkv; Th = Wdh; Tl = Wdl; K = 2048; N = 512; gx = q & 15; gy = q >> 4;
  } else if (bx < 14336) {
    const int q = bx - 13312;
    W = Wuk; Th = Wukh; Tl = Wukl; K = 512; N = 2048; gx = q & 63; gy = q >> 6;
  } else if (bx < 15360) {
    const int q = bx - 14336;
    W = Wuv; Th = Wuvt; K = 512; N = 2048; gx = q & 63; gy = q >> 6;
  } else {
    const int q = bx - 15360;
    W = Wo; Th = Wot; K = 2048; N = 2048; gx = q & 63; gy = q >> 6;
  }
  const int tx = tid & 31, ty0 = tid >> 5;
#pragma unroll
  for (int i = 0; i < 4; ++i) {
    const int ty = ty0 + i * 8;
    t[ty][tx] = W[(size_t)(gy * 32 + ty) * N + gx * 32 + tx];
  }
  __syncthreads();
#pragma unroll
  for (int i = 0; i < 4; ++i) {
    const int ty = ty0 + i * 8;
    const float v = t[tx][ty];
    const size_t o = (size_t)(gx * 32 + ty) * K + gy * 32 + tx;
    const u16 hi = f2bf(v);
    Th[o] = hi;
    if (Tl) Tl[o] = f2bf(v - bf2f(hi));
  }
}

// ------------- attention v9: 48KB LDS (St[64][64], no fm) + T5 setprio ------
// LDS = 32KB KP + 16KB St = 49152B exactly. If alloc granularity <= 16KB this
// enables 3 blocks/CU (falsifier: OccupancyPercent stays ~38).
__device__ __forceinline__ u32 fmap(float f) {
  u32 b = __float_as_uint(f);
  return (b & 0x80000000u) ? ~b : (b | 0x80000000u);
}
__device__ __forceinline__ float unfmap(u32 u) {
  return (u & 0x80000000u) ? __uint_as_float(u ^ 0x80000000u)
                           : __uint_as_float(~u);
}

__global__ __launch_bounds__(512, 4) void attn_v9(
    const u16* __restrict__ qbh, const u16* __restrict__ qbl,
    const u16* __restrict__ khi, const u16* __restrict__ klo,
    const u16* __restrict__ vt, const int* __restrict__ forget,
    const int* __restrict__ topk, u16* __restrict__ ab) {
  __shared__ u16 KP[2 * 64 * 128];  // 32KB: Kh|Kl; later P[64][256]
  __shared__ float St[64 * 64];     // 16KB: scores; later V^T tile
  u16* const Kh = KP;
  u16* const Kl = KP + 64 * 128;
  u16* const Pb = KP;
  u16* const Vts = (u16*)St;  // single V^T buffer (after scores captured)

  const float scale = 0.08838834764831845f;  // 1/sqrt(128)
  const int tid = threadIdx.x, lane = tid & 63, wv = tid >> 6;
  const int lin = blockIdx.x + 32 * (blockIdx.y + 16 * blockIdx.z);
  const int nl = (lin & 7) * 128 + (lin >> 3);
  const int q0 = (nl & 31) * 64;
  const int h = (nl >> 5) & 15;
  const int b = nl >> 9;
  const int mt = wv >> 1, nh = wv & 1;
  const int l15 = lane & 15, lhi = lane >> 4;
  const int nt = (q0 >= 256) ? 4 : (q0 / 64 + 1);
  const int KTOP = topk[0];

  auto kbase = [&](int t) {
    return (q0 >= 256) ? (t == 0 ? 0 : q0 + t * 64 - 192) : t * 64;
  };
  auto stage_k = [&](int t) {
    const int kbt = kbase(t);
#pragma unroll
    for (int p = 0; p < 2; ++p) {
      const int c = p * 512 + tid;
      const int row = c >> 4, sl = c & 15;
      const size_t src = (size_t)(b * SS + kbt + row) * HIDC + h * HD +
                         ((sl ^ (row & 7)) << 3);
      load_lds16(khi + src, Kh + (p * 512 + wv * 64) * 8);
      load_lds16(klo + src, Kl + (p * 512 + wv * 64) * 8);
    }
  };
  auto stage_vt = [&](int t) {
    const int kbt = kbase(t);
#pragma unroll
    for (int p = 0; p < 2; ++p) {
      const int c = p * 512 + tid;
      const int d = c >> 3, sl = c & 7;
      const u16* src = vt + ((size_t)(b * HIDC + h * HD + d)) * SS + kbt +
                       ((sl ^ (d & 7)) << 3);
      load_lds16(src, Vts + (p * 512 + wv * 64) * 8);
    }
  };

  u32 koff[4][2];
#pragma unroll
  for (int kt = 0; kt < 4; ++kt)
#pragma unroll
    for (int ni = 0; ni < 2; ++ni) {
      const int key = nh * 32 + ni * 16 + l15;
      const int kg = kt * 4 + lhi;
      koff[kt][ni] = key * 128 + ((kg ^ (key & 7)) << 3);
    }
  const int arow = mt * 16 + l15;
  u32 pboff[2];
#pragma unroll
  for (int ks = 0; ks < 2; ++ks)
    pboff[ks] = arow * 256 + (((ks * 4 + lhi) ^ (arow & 7)) << 3);
  u32 voff[2][4];
#pragma unroll
  for (int ks = 0; ks < 2; ++ks)
#pragma unroll
    for (int t2 = 0; t2 < 4; ++t2) {
      const int drow = nh * 64 + t2 * 16 + l15;
      voff[ks][t2] = drow * 64 + (((ks * 4 + lhi) ^ (drow & 7)) << 3);
    }
  const u32 stw = (u32)(mt * 16 + lhi * 4) * 64 + nh * 32 + l15;

  u16x8 ah[4], al[4];
  const size_t qrow = (size_t)(b * SS + q0 + mt * 16 + l15) * HIDC + h * HD;
#pragma unroll
  for (int kt = 0; kt < 4; ++kt) {
    ah[kt] = *(const u16x8*)(qbh + qrow + kt * 32 + lhi * 8);
    al[kt] = *(const u16x8*)(qbl + qrow + kt * 32 + lhi * 8);
  }

  u32 uu[8][4];
#pragma unroll
  for (int i = 0; i < 8; ++i)
#pragma unroll
    for (int j = 0; j < 4; ++j) uu[i][j] = 0u;

  stage_k(0);
#pragma unroll
  for (int t = 0; t < 4; ++t) {
    if (t < nt) {
      asm volatile("s_waitcnt vmcnt(0)" ::: "memory");
      __syncthreads();

      f32x4 acc0 = (f32x4){0.f, 0.f, 0.f, 0.f};
      f32x4 acc1 = (f32x4){0.f, 0.f, 0.f, 0.f};
      __builtin_amdgcn_s_setprio(1);
#pragma unroll
      for (int kt = 0; kt < 4; ++kt) {
#pragma unroll
        for (int ni = 0; ni < 2; ++ni) {
          const bf16x8 bh = *(const bf16x8*)(Kh + koff[kt][ni]);
          const bf16x8 bl = *(const bf16x8*)(Kl + koff[kt][ni]);
          f32x4 a = ni ? acc1 : acc0;
          a = __builtin_amdgcn_mfma_f32_16x16x32_bf16(
              __builtin_bit_cast(bf16x8, ah[kt]), bh, a, 0, 0, 0);
          a = __builtin_amdgcn_mfma_f32_16x16x32_bf16(
              __builtin_bit_cast(bf16x8, ah[kt]), bl, a, 0, 0, 0);
          a = __builtin_amdgcn_mfma_f32_16x16x32_bf16(
              __builtin_bit_cast(bf16x8, al[kt]), bh, a, 0, 0, 0);
          if (ni) acc1 = a; else acc0 = a;
        }
      }
      __builtin_amdgcn_s_setprio(0);
#pragma unroll
      for (int ni = 0; ni < 2; ++ni)
#pragma unroll
        for (int r = 0; r < 4; ++r)
          St[stw + r * 64 + ni * 16] = (ni ? acc1 : acc0)[r] * scale;
      __syncthreads();  // St complete; all K reads done

      if (t + 1 < nt) stage_k(t + 1);

      const int kbt = kbase(t);
      const int key = kbt + lane;
      const int fg = forget[b * SS + key];  // coalesced, L2-hot
      const bool fok = !(fg != 0 && key >= 16);
      const bool sk = key < 16;
#pragma unroll
      for (int i = 0; i < 8; ++i) {
        const int qi = q0 + wv * 8 + i;
        const bool valid =
            key <= qi && (key >= qi - 127 || sk) && (fok || key == qi);
        uu[i][t] = fmap(valid ? St[(wv * 8 + i) * 64 + lane] : NEGV);
      }
    }
  }
  __syncthreads();  // captures done; St dead -> V buffer

  stage_vt(0);  // V tile 0 rides under the search

  u32 tl[8], th[8];
#pragma unroll
  for (int i = 0; i < 8; ++i) { tl[i] = 0u; th[i] = 0xFFFFFFFFu; }
  for (int it = 0; it < 32; ++it) {
    bool any = false;
#pragma unroll
    for (int i = 0; i < 8; ++i) {
      if (tl[i] < th[i]) {
        any = true;
        const u32 mid = tl[i] + ((th[i] - tl[i]) >> 1) + 1u;
        const int cnt = __popcll(__ballot(uu[i][0] >= mid)) +
                        __popcll(__ballot(uu[i][1] >= mid)) +
                        __popcll(__ballot(uu[i][2] >= mid)) +
                        __popcll(__ballot(uu[i][3] >= mid));
        if (cnt == KTOP) {
          tl[i] = mid;
          th[i] = mid;  // kept set {u>=mid} has exactly KTOP elems == ref set
        } else if (cnt > KTOP) {
          tl[i] = mid;
        } else {
          th[i] = mid - 1u;
        }
      }
    }
    if (!any) break;
  }

#pragma unroll
  for (int i = 0; i < 8; ++i) {
    const int r = wv * 8 + i;
    float sv[4], m = NEGV;
#pragma unroll
    for (int j = 0; j < 4; ++j) {
      sv[j] = unfmap(uu[i][j]);
      m = (uu[i][j] >= tl[i]) ? fmaxf(m, sv[j]) : m;
    }
#pragma unroll
    for (int off = 32; off > 0; off >>= 1) m = fmaxf(m, __shfl_xor(m, off));
    float e[4], z = 0.f;
#pragma unroll
    for (int j = 0; j < 4; ++j) {
      e[j] = (uu[i][j] >= tl[i]) ? __expf(sv[j] - m) : 0.f;
      z += e[j];
    }
#pragma unroll
    for (int off = 32; off > 0; off >>= 1) z += __shfl_xor(z, off);
    const float rz = 1.f / z;
#pragma unroll
    for (int j = 0; j < 4; ++j) {
      const int c = lane + 64 * j;
      const int sl = c >> 3;
      Pb[r * 256 + ((sl ^ (r & 7)) << 3) + (c & 7)] = f2bf(e[j] * rz);
    }
  }

  asm volatile("s_waitcnt vmcnt(0)" ::: "memory");
  __syncthreads();  // P visible + V tile 0 staged

  // ---- PV via MFMA, single V buffer: MFMA(t) -> bar -> stage(t+1) -> drain
  f32x4 pacc[4];
#pragma unroll
  for (int t2 = 0; t2 < 4; ++t2) pacc[t2] = (f32x4){0.f, 0.f, 0.f, 0.f};

#pragma unroll
  for (int t = 0; t < 4; ++t) {
    if (t < nt) {
      __builtin_amdgcn_s_setprio(1);
#pragma unroll
      for (int ks = 0; ks < 2; ++ks) {
        const bf16x8 af = *(const bf16x8*)(Pb + pboff[ks] + t * 64);
#pragma unroll
        for (int t2 = 0; t2 < 4; ++t2) {
          const bf16x8 bf_ = *(const bf16x8*)(Vts + voff[ks][t2]);
          pacc[t2] = __builtin_amdgcn_mfma_f32_16x16x32_bf16(af, bf_, pacc[t2],
                                                             0, 0, 0);
        }
      }
      __builtin_amdgcn_s_setprio(0);
      if (t + 1 < nt) {
        __syncthreads();  // all reads of Vts done
        stage_vt(t + 1);
        asm volatile("s_waitcnt vmcnt(0)" ::: "memory");
        __syncthreads();
      }
    }
  }

#pragma unroll
  for (int t2 = 0; t2 < 4; ++t2)
#pragma unroll
    for (int r = 0; r < 4; ++r) {
      const int row = q0 + mt * 16 + lhi * 4 + r;
      const int col = h * HD + nh * 64 + t2 * 16 + l15;
      ab[(size_t)(b * SS + row) * HIDC + col] = f2bf(pacc[t2][r]);
    }
}

// ----------------------------------------------------------------------------
extern "C" void kernel_launch(void* const* d_in, const int* in_sizes, int n_in,
                              void* d_out, int out_size, void* d_ws, size_t ws_size,
                              hipStream_t stream) {
  const float* x = (const float*)d_in[0];
  const float* W_q = (const float*)d_in[1];
  const float* W_dkv = (const float*)d_in[2];
  const float* W_uk = (const float*)d_in[3];
  const float* W_uv = (const float*)d_in[4];
  const float* W_o = (const float*)d_in[5];
  const int* forget = (const int*)d_in[6];
  const int* topk = (const int*)d_in[7];
  float* out = (float*)d_out;

  char* p = (char*)d_ws;
  auto take = [&](size_t n) {
    char* r = p;
    p += (n + 255) & ~(size_t)255;
    return r;
  };

  u16* xb_hi = (u16*)take((size_t)MROWS * HIDC * 2);  // 16MB
  u16* xb_lo = (u16*)take((size_t)MROWS * HIDC * 2);  // 16MB
  u16* Wqh = (u16*)take((size_t)HIDC * HIDC * 2);     // 8MB
  u16* Wql = (u16*)take((size_t)HIDC * HIDC * 2);     // 8MB
  u16* Wdh = (u16*)take((size_t)LATC * HIDC * 2);     // 2MB
  u16* Wdl = (u16*)take((size_t)LATC * HIDC * 2);
  u16* Wukh = (u16*)take((size_t)HIDC * LATC * 2);    // 2MB
  u16* Wukl = (u16*)take((size_t)HIDC * LATC * 2);
  u16* Wuvt = (u16*)take((size_t)HIDC * LATC * 2);    // 2MB
  u16* Wot = (u16*)take((size_t)HIDC * HIDC * 2);     // 8MB
  u16* qbh = (u16*)take((size_t)MROWS * HIDC * 2);    // 16MB
  u16* qbl = (u16*)take((size_t)MROWS * HIDC * 2);    // 16MB
  u16* cbh = (u16*)take((size_t)MROWS * LATC * 2);    // 4MB
  u16* cbl = (u16*)take((size_t)MROWS * LATC * 2);    // 4MB
  u16* vt = (u16*)take((size_t)BB * HIDC * SS * 2);   // 16MB
  u16* khi = xb_hi;  // alias: xb dead after q/c GEMMs
  u16* klo = xb_lo;
  u16* ab = Wqh;     // alias: Wq dead after q-GEMM (16MB spans Wqh+Wql)

  // 1) merged prep: x split + all 5 weight transposes
  prep_all<<<dim3(19456), dim3(256), 0, stream>>>(
      x, xb_hi, xb_lo, W_q, Wqh, Wql, W_dkv, Wdh, Wdl, W_uk, Wukh, Wukl,
      W_uv, Wuvt, W_o, Wot);
  // 2) q = x @ W_q -> pre-split qbh/qbl
  gemm_split_bt<128, 3><<<dim3(MROWS / 128, HIDC / 128), 256, 0, stream>>>(
      xb_hi, xb_lo, Wqh, Wql, nullptr, qbh, qbl, MROWS, HIDC, HIDC);
  // 3) c = x @ W_dkv -> pre-split cbh/cbl (TN=64, 256 blocks)
  gemm_split_bt<64, 3><<<dim3(MROWS / 128, LATC / 64), 256, 0, stream>>>(
      xb_hi, xb_lo, Wdh, Wdl, nullptr, cbh, cbl, MROWS, LATC, HIDC);
  // 4) k = c @ W_uk -> pre-split khi/klo (aliases xb, dead now)
  gemm_split_bt<128, 3><<<dim3(MROWS / 128, HIDC / 128), 256, 0, stream>>>(
      cbh, cbl, Wukh, Wukl, nullptr, khi, klo, MROWS, HIDC, LATC);
  // 5) v^T = W_uv^T @ c_b^T, both batches in one dispatch (blockIdx.z)
  gemm_bt<2><<<dim3(HIDC / 128, SS / 128, BB), 256, 0, stream>>>(
      Wuvt, cbh, nullptr, vt, HIDC, SS, LATC,
      0, (size_t)SS * LATC, (size_t)HIDC * SS);
  // 6) attention v9 -> ab (bf16), aliases Wq (dead)
  attn_v9<<<dim3(SS / 64, NH, BB), dim3(512), 0, stream>>>(
      qbh, qbl, khi, klo, vt, forget, topk, ab);
  // 7) out = attn_out @ W_o
  gemm_bt<0><<<dim3(MROWS / 128, HIDC / 128), 256, 0, stream>>>(
      ab, Wot, out, nullptr, MROWS, HIDC, HIDC, 0, 0, 0);
}

// Round 15
// 307.950 us; speedup vs baseline: 1.0083x; 1.0083x over previous
//
#include <hip/hip_runtime.h>
#include <hip/hip_bf16.h>

typedef unsigned short u16;
typedef unsigned int u32;
typedef unsigned long long u64;
typedef __bf16 bf16x8 __attribute__((ext_vector_type(8)));
typedef float f32x4 __attribute__((ext_vector_type(4)));
typedef u16 u16x4 __attribute__((ext_vector_type(4)));
typedef u16 u16x8 __attribute__((ext_vector_type(8)));

static constexpr int BB = 2, SS = 2048, HIDC = 2048, LATC = 512, NH = 16, HD = 128;
static constexpr int MROWS = BB * SS;  // 4096
static constexpr float NEGV = -1e9f;

__device__ __forceinline__ u16 f2bf(float f) {
  __hip_bfloat16 h = __float2bfloat16(f);
  return __builtin_bit_cast(u16, h);
}
__device__ __forceinline__ float bf2f(u16 u) {
  return __uint_as_float(((u32)u) << 16);
}
__device__ __forceinline__ void load_lds16(const void* g, void* l) {
  __builtin_amdgcn_global_load_lds(
      (const __attribute__((address_space(1))) void*)g,
      (__attribute__((address_space(3))) void*)l, 16, 0, 0);
}

// ---------------- plain GEMM: C[M][N] = A[M][K] @ Bt[N][K]^T ----------------
// MODE 0: C = f32 store; MODE 2: Cb = bf16 store. Batch via blockIdx.z strides.
// NOTE: natural separate dispatches in natural block order are measured-best:
// XCD remap (R9), interleaved merge (R11), concat merge (R12) all regressed.
template <int MODE>
__global__ __launch_bounds__(256, 2) void gemm_bt(
    const u16* __restrict__ A, const u16* __restrict__ Bt,
    float* __restrict__ C, u16* __restrict__ Cb, int M, int N, int K,
    size_t sA, size_t sB, size_t sC) {
  __shared__ u16 As[128 * 64];
  __shared__ u16 Bs[128 * 64];
  const int tid = threadIdx.x;
  const int lane = tid & 63;
  const int wv = tid >> 6;
  const int wr = wv >> 1, wc = wv & 1;
  const int m0 = blockIdx.x * 128, n0 = blockIdx.y * 128;
  A += sA * blockIdx.z;
  Bt += sB * blockIdx.z;
  if constexpr (MODE == 0) C += sC * blockIdx.z;
  if constexpr (MODE == 2) Cb += sC * blockIdx.z;

  f32x4 acc[4][4];
#pragma unroll
  for (int i = 0; i < 4; ++i)
#pragma unroll
    for (int j = 0; j < 4; ++j) acc[i][j] = (f32x4){0.f, 0.f, 0.f, 0.f};

  int srow[4], sgc[4];
#pragma unroll
  for (int j = 0; j < 4; ++j) {
    int e = j * 2048 + tid * 8;
    int row = e >> 6;
    int slot = (e >> 3) & 7;
    srow[j] = row;
    sgc[j] = (slot ^ (row & 7)) * 8;
  }

  for (int k0 = 0; k0 < K; k0 += 64) {
    __syncthreads();
#pragma unroll
    for (int j = 0; j < 4; ++j) {
      const u16* ga = A + (size_t)(m0 + srow[j]) * K + k0 + sgc[j];
      const u16* gb = Bt + (size_t)(n0 + srow[j]) * K + k0 + sgc[j];
      load_lds16(ga, &As[j * 2048 + wv * 512]);
      load_lds16(gb, &Bs[j * 2048 + wv * 512]);
    }
    asm volatile("s_waitcnt vmcnt(0)" ::: "memory");
    __syncthreads();

#pragma unroll
    for (int kk = 0; kk < 2; ++kk) {
      bf16x8 afr[4], bfr[4];
      const int kg = kk * 4 + (lane >> 4);
#pragma unroll
      for (int i = 0; i < 4; ++i) {
        int ar = wr * 64 + i * 16 + (lane & 15);
        afr[i] = *(const bf16x8*)&As[ar * 64 + ((kg ^ (ar & 7)) << 3)];
        int br = wc * 64 + i * 16 + (lane & 15);
        bfr[i] = *(const bf16x8*)&Bs[br * 64 + ((kg ^ (br & 7)) << 3)];
      }
#pragma unroll
      for (int mi = 0; mi < 4; ++mi)
#pragma unroll
        for (int ni = 0; ni < 4; ++ni)
          acc[mi][ni] = __builtin_amdgcn_mfma_f32_16x16x32_bf16(
              afr[mi], bfr[ni], acc[mi][ni], 0, 0, 0);
    }
  }

#pragma unroll
  for (int mi = 0; mi < 4; ++mi) {
#pragma unroll
    for (int ni = 0; ni < 4; ++ni) {
      const int row = m0 + wr * 64 + mi * 16 + (lane >> 4) * 4;
      const int col = n0 + wc * 64 + ni * 16 + (lane & 15);
#pragma unroll
      for (int r = 0; r < 4; ++r) {
        size_t off = (size_t)(row + r) * N + col;
        if constexpr (MODE == 0) C[off] = acc[mi][ni][r];
        if constexpr (MODE == 2) Cb[off] = f2bf(acc[mi][ni][r]);
      }
    }
  }
}

// -------- fused split GEMM: C = Ah@Bh^T + Ah@Bl^T + Al@Bh^T (f32-accurate) --
template <int TN, int MODE>
__global__ __launch_bounds__(256, 2) void gemm_split_bt(
    const u16* __restrict__ Ah, const u16* __restrict__ Al,
    const u16* __restrict__ Bth, const u16* __restrict__ Btl,
    float* __restrict__ C, u16* __restrict__ Ch, u16* __restrict__ Cl,
    int M, int N, int K) {
  constexpr int NI = TN / 32;
  __shared__ u16 Ash[128 * 64];
  __shared__ u16 Asl[128 * 64];
  __shared__ u16 Bsh[TN * 64];
  __shared__ u16 Bsl[TN * 64];
  const int tid = threadIdx.x;
  const int lane = tid & 63;
  const int wv = tid >> 6;
  const int wr = wv >> 1, wc = wv & 1;
  const int l15 = lane & 15, lhi = lane >> 4;
  const int m0 = blockIdx.x * 128, n0 = blockIdx.y * TN;

  f32x4 acc[4][NI];
#pragma unroll
  for (int i = 0; i < 4; ++i)
#pragma unroll
    for (int j = 0; j < NI; ++j) acc[i][j] = (f32x4){0.f, 0.f, 0.f, 0.f};

  int srow[4], sgc[4];
#pragma unroll
  for (int j = 0; j < 4; ++j) {
    int e = j * 2048 + tid * 8;
    int row = e >> 6;
    int slot = (e >> 3) & 7;
    srow[j] = row;
    sgc[j] = (slot ^ (row & 7)) * 8;
  }

  for (int k0 = 0; k0 < K; k0 += 64) {
    __syncthreads();
#pragma unroll
    for (int j = 0; j < 4; ++j) {
      const size_t ao = (size_t)(m0 + srow[j]) * K + k0 + sgc[j];
      load_lds16(Ah + ao, &Ash[j * 2048 + wv * 512]);
      load_lds16(Al + ao, &Asl[j * 2048 + wv * 512]);
    }
#pragma unroll
    for (int j = 0; j < NI; ++j) {
      const size_t bo = (size_t)(n0 + srow[j]) * K + k0 + sgc[j];
      load_lds16(Bth + bo, &Bsh[j * 2048 + wv * 512]);
      load_lds16(Btl + bo, &Bsl[j * 2048 + wv * 512]);
    }
    asm volatile("s_waitcnt vmcnt(0)" ::: "memory");
    __syncthreads();

#pragma unroll
    for (int kk = 0; kk < 2; ++kk) {
      const int kg = kk * 4 + lhi;
      bf16x8 afh[4], afl[4], bfh[NI], bfl[NI];
#pragma unroll
      for (int i = 0; i < 4; ++i) {
        const int ar = wr * 64 + i * 16 + l15;
        const int off = ar * 64 + ((kg ^ (ar & 7)) << 3);
        afh[i] = *(const bf16x8*)&Ash[off];
        afl[i] = *(const bf16x8*)&Asl[off];
      }
#pragma unroll
      for (int i = 0; i < NI; ++i) {
        const int br = wc * (TN / 2) + i * 16 + l15;
        const int off = br * 64 + ((kg ^ (br & 7)) << 3);
        bfh[i] = *(const bf16x8*)&Bsh[off];
        bfl[i] = *(const bf16x8*)&Bsl[off];
      }
#pragma unroll
      for (int mi = 0; mi < 4; ++mi)
#pragma unroll
        for (int ni = 0; ni < NI; ++ni) {
          acc[mi][ni] = __builtin_amdgcn_mfma_f32_16x16x32_bf16(
              afh[mi], bfh[ni], acc[mi][ni], 0, 0, 0);
          acc[mi][ni] = __builtin_amdgcn_mfma_f32_16x16x32_bf16(
              afh[mi], bfl[ni], acc[mi][ni], 0, 0, 0);
          acc[mi][ni] = __builtin_amdgcn_mfma_f32_16x16x32_bf16(
              afl[mi], bfh[ni], acc[mi][ni], 0, 0, 0);
        }
    }
  }

#pragma unroll
  for (int mi = 0; mi < 4; ++mi) {
#pragma unroll
    for (int ni = 0; ni < NI; ++ni) {
      const int row = m0 + wr * 64 + mi * 16 + lhi * 4;
      const int col = n0 + wc * (TN / 2) + ni * 16 + l15;
#pragma unroll
      for (int r = 0; r < 4; ++r) {
        const size_t off = (size_t)(row + r) * N + col;
        const float v = acc[mi][ni][r];
        if constexpr (MODE == 0) C[off] = v;
        if constexpr (MODE == 3) {
          const u16 hh = f2bf(v);
          Ch[off] = hh;
          Cl[off] = f2bf(v - bf2f(hh));
        }
      }
    }
  }
}

// ------------- merged prep: x split + all weight transposes (one dispatch) --
__global__ __launch_bounds__(256) void prep_all(
    const float* __restrict__ x, u16* __restrict__ xh, u16* __restrict__ xl,
    const float* __restrict__ Wq, u16* __restrict__ Wqh, u16* __restrict__ Wql,
    const float* __restrict__ Wdkv, u16* __restrict__ Wdh, u16* __restrict__ Wdl,
    const float* __restrict__ Wuk, u16* __restrict__ Wukh, u16* __restrict__ Wukl,
    const float* __restrict__ Wuv, u16* __restrict__ Wuvt,
    const float* __restrict__ Wo, u16* __restrict__ Wot) {
  const int bx = blockIdx.x, tid = threadIdx.x;
  if (bx < 8192) {
    const size_t i = ((size_t)bx * 256 + tid) * 4;
    f32x4 v = *(const f32x4*)(x + i);
    u16x4 hh, ll;
#pragma unroll
    for (int e = 0; e < 4; ++e) {
      const u16 hi = f2bf(v[e]);
      hh[e] = hi;
      ll[e] = f2bf(v[e] - bf2f(hi));
    }
    *(u16x4*)(xh + i) = hh;
    *(u16x4*)(xl + i) = ll;
    return;
  }
  __shared__ float t[32][33];
  const float* W;
  u16 *Th, *Tl = nullptr;
  int K, N, gx, gy;
  if (bx < 12288) {
    const int q = bx - 8192;
    W = Wq; Th = Wqh; Tl = Wql; K = 2048; N = 2048; gx = q & 63; gy = q >> 6;
  } else if (bx < 13312) {
    const int q = bx - 12288;
    W = Wdkv; Th = Wdh; Tl = Wdl; K = 2048; N = 512; gx = q & 15; gy = q >> 4;
  } else if (bx < 14336) {
    const int q = bx - 13312;
    W = Wuk; Th = Wukh; Tl = Wukl; K = 512; N = 2048; gx = q & 63; gy = q >> 6;
  } else if (bx < 15360) {
    const int q = bx - 14336;
    W = Wuv; Th = Wuvt; K = 512; N = 2048; gx = q & 63; gy = q >> 6;
  } else {
    const int q = bx - 15360;
    W = Wo; Th = Wot; K = 2048; N = 2048; gx = q & 63; gy = q >> 6;
  }
  const int tx = tid & 31, ty0 = tid >> 5;
#pragma unroll
  for (int i = 0; i < 4; ++i) {
    const int ty = ty0 + i * 8;
    t[ty][tx] = W[(size_t)(gy * 32 + ty) * N + gx * 32 + tx];
  }
  __syncthreads();
#pragma unroll
  for (int i = 0; i < 4; ++i) {
    const int ty = ty0 + i * 8;
    const float v = t[tx][ty];
    const size_t o = (size_t)(gx * 32 + ty) * K + gy * 32 + tx;
    const u16 hi = f2bf(v);
    Th[o] = hi;
    if (Tl) Tl[o] = f2bf(v - bf2f(hi));
  }
}

// ------------- attention v7 (best measured: R10) -----------------------------
__device__ __forceinline__ u32 fmap(float f) {
  u32 b = __float_as_uint(f);
  return (b & 0x80000000u) ? ~b : (b | 0x80000000u);
}
__device__ __forceinline__ float unfmap(u32 u) {
  return (u & 0x80000000u) ? __uint_as_float(u ^ 0x80000000u)
                           : __uint_as_float(~u);
}

__global__ __launch_bounds__(512, 2) void attn_v7(
    const u16* __restrict__ qbh, const u16* __restrict__ qbl,
    const u16* __restrict__ khi, const u16* __restrict__ klo,
    const u16* __restrict__ vt, const int* __restrict__ forget,
    const int* __restrict__ topk, u16* __restrict__ ab) {
  __shared__ u16 KP[2 * 64 * 128];
  __shared__ float St[64 * 68];
  __shared__ u16 Vb1[64 * 128];
  __shared__ int fm[256];
  u16* const Kh = KP;
  u16* const Kl = KP + 64 * 128;
  u16* const Pb = KP;
  u16* const Vt0 = (u16*)St;

  const float scale = 0.08838834764831845f;
  const int tid = threadIdx.x, lane = tid & 63, wv = tid >> 6;
  const int lin = blockIdx.x + 32 * (blockIdx.y + 16 * blockIdx.z);
  const int nl = (lin & 7) * 128 + (lin >> 3);
  const int q0 = (nl & 31) * 64;
  const int h = (nl >> 5) & 15;
  const int b = nl >> 9;
  const int mt = wv >> 1, nh = wv & 1;
  const int l15 = lane & 15, lhi = lane >> 4;
  const int nt = (q0 >= 256) ? 4 : (q0 / 64 + 1);
  const int KTOP = topk[0];

  auto kbase = [&](int t) {
    return (q0 >= 256) ? (t == 0 ? 0 : q0 + t * 64 - 192) : t * 64;
  };
  auto stage_k = [&](int t) {
    const int kbt = kbase(t);
#pragma unroll
    for (int p = 0; p < 2; ++p) {
      const int c = p * 512 + tid;
      const int row = c >> 4, sl = c & 15;
      const size_t src = (size_t)(b * SS + kbt + row) * HIDC + h * HD +
                         ((sl ^ (row & 7)) << 3);
      load_lds16(khi + src, Kh + (p * 512 + wv * 64) * 8);
      load_lds16(klo + src, Kl + (p * 512 + wv * 64) * 8);
    }
  };
  auto stage_vt = [&](int t, u16* dst) {
    const int kbt = kbase(t);
#pragma unroll
    for (int p = 0; p < 2; ++p) {
      const int c = p * 512 + tid;
      const int d = c >> 3, sl = c & 7;
      const u16* src = vt + ((size_t)(b * HIDC + h * HD + d)) * SS + kbt +
                       ((sl ^ (d & 7)) << 3);
      load_lds16(src, dst + (p * 512 + wv * 64) * 8);
    }
  };

  if (tid < 256)
    fm[tid] = ((tid >> 6) < nt) ? forget[b * SS + kbase(tid >> 6) + (tid & 63)] : 0;

  u32 koff[4][2];
#pragma unroll
  for (int kt = 0; kt < 4; ++kt)
#pragma unroll
    for (int ni = 0; ni < 2; ++ni) {
      const int key = nh * 32 + ni * 16 + l15;
      const int kg = kt * 4 + lhi;
      koff[kt][ni] = key * 128 + ((kg ^ (key & 7)) << 3);
    }
  const int arow = mt * 16 + l15;
  u32 pboff[2];
#pragma unroll
  for (int ks = 0; ks < 2; ++ks)
    pboff[ks] = arow * 256 + (((ks * 4 + lhi) ^ (arow & 7)) << 3);
  u32 voff[2][4];
#pragma unroll
  for (int ks = 0; ks < 2; ++ks)
#pragma unroll
    for (int t2 = 0; t2 < 4; ++t2) {
      const int drow = nh * 64 + t2 * 16 + l15;
      voff[ks][t2] = drow * 64 + (((ks * 4 + lhi) ^ (drow & 7)) << 3);
    }
  const u32 stw = (u32)(mt * 16 + lhi * 4) * 68 + nh * 32 + l15;

  u16x8 ah[4], al[4];
  const size_t qrow = (size_t)(b * SS + q0 + mt * 16 + l15) * HIDC + h * HD;
#pragma unroll
  for (int kt = 0; kt < 4; ++kt) {
    ah[kt] = *(const u16x8*)(qbh + qrow + kt * 32 + lhi * 8);
    al[kt] = *(const u16x8*)(qbl + qrow + kt * 32 + lhi * 8);
  }

  u32 uu[8][4];
#pragma unroll
  for (int i = 0; i < 8; ++i)
#pragma unroll
    for (int j = 0; j < 4; ++j) uu[i][j] = 0u;

  stage_k(0);
  stage_vt(0, Vb1);

#pragma unroll
  for (int t = 0; t < 4; ++t) {
    if (t < nt) {
      asm volatile("s_waitcnt vmcnt(0)" ::: "memory");
      __syncthreads();

      f32x4 acc0 = (f32x4){0.f, 0.f, 0.f, 0.f};
      f32x4 acc1 = (f32x4){0.f, 0.f, 0.f, 0.f};
#pragma unroll
      for (int kt = 0; kt < 4; ++kt) {
#pragma unroll
        for (int ni = 0; ni < 2; ++ni) {
          const bf16x8 bh = *(const bf16x8*)(Kh + koff[kt][ni]);
          const bf16x8 bl = *(const bf16x8*)(Kl + koff[kt][ni]);
          f32x4 a = ni ? acc1 : acc0;
          a = __builtin_amdgcn_mfma_f32_16x16x32_bf16(
              __builtin_bit_cast(bf16x8, ah[kt]), bh, a, 0, 0, 0);
          a = __builtin_amdgcn_mfma_f32_16x16x32_bf16(
              __builtin_bit_cast(bf16x8, ah[kt]), bl, a, 0, 0, 0);
          a = __builtin_amdgcn_mfma_f32_16x16x32_bf16(
              __builtin_bit_cast(bf16x8, al[kt]), bh, a, 0, 0, 0);
          if (ni) acc1 = a; else acc0 = a;
        }
      }
#pragma unroll
      for (int ni = 0; ni < 2; ++ni)
#pragma unroll
        for (int r = 0; r < 4; ++r)
          St[stw + r * 68 + ni * 16] = (ni ? acc1 : acc0)[r] * scale;
      __syncthreads();

      if (t + 1 < nt) stage_k(t + 1);

      const int kbt = kbase(t);
      const int key = kbt + lane;
      const bool fok = !(fm[t * 64 + lane] != 0 && key >= 16);
      const bool sk = key < 16;
#pragma unroll
      for (int i = 0; i < 8; ++i) {
        const int qi = q0 + wv * 8 + i;
        const bool valid =
            key <= qi && (key >= qi - 127 || sk) && (fok || key == qi);
        uu[i][t] = fmap(valid ? St[(wv * 8 + i) * 68 + lane] : NEGV);
      }
    }
  }
  __syncthreads();

  if (nt > 1) stage_vt(1, Vt0);

  u32 tl[8], th[8];
#pragma unroll
  for (int i = 0; i < 8; ++i) { tl[i] = 0u; th[i] = 0xFFFFFFFFu; }
  for (int it = 0; it < 32; ++it) {
    bool any = false;
#pragma unroll
    for (int i = 0; i < 8; ++i) {
      if (tl[i] < th[i]) {
        any = true;
        const u32 mid = tl[i] + ((th[i] - tl[i]) >> 1) + 1u;
        const int cnt = __popcll(__ballot(uu[i][0] >= mid)) +
                        __popcll(__ballot(uu[i][1] >= mid)) +
                        __popcll(__ballot(uu[i][2] >= mid)) +
                        __popcll(__ballot(uu[i][3] >= mid));
        if (cnt == KTOP) {
          tl[i] = mid;
          th[i] = mid;
        } else if (cnt > KTOP) {
          tl[i] = mid;
        } else {
          th[i] = mid - 1u;
        }
      }
    }
    if (!any) break;
  }

#pragma unroll
  for (int i = 0; i < 8; ++i) {
    const int r = wv * 8 + i;
    float sv[4], m = NEGV;
#pragma unroll
    for (int j = 0; j < 4; ++j) {
      sv[j] = unfmap(uu[i][j]);
      m = (uu[i][j] >= tl[i]) ? fmaxf(m, sv[j]) : m;
    }
#pragma unroll
    for (int off = 32; off > 0; off >>= 1) m = fmaxf(m, __shfl_xor(m, off));
    float e[4], z = 0.f;
#pragma unroll
    for (int j = 0; j < 4; ++j) {
      e[j] = (uu[i][j] >= tl[i]) ? __expf(sv[j] - m) : 0.f;
      z += e[j];
    }
#pragma unroll
    for (int off = 32; off > 0; off >>= 1) z += __shfl_xor(z, off);
    const float rz = 1.f / z;
#pragma unroll
    for (int j = 0; j < 4; ++j) {
      const int c = lane + 64 * j;
      const int sl = c >> 3;
      Pb[r * 256 + ((sl ^ (r & 7)) << 3) + (c & 7)] = f2bf(e[j] * rz);
    }
  }

  asm volatile("s_waitcnt vmcnt(0)" ::: "memory");
  __syncthreads();

  f32x4 pacc[4];
#pragma unroll
  for (int t2 = 0; t2 < 4; ++t2) pacc[t2] = (f32x4){0.f, 0.f, 0.f, 0.f};

#pragma unroll
  for (int t = 0; t < 4; ++t) {
    if (t < nt) {
      if (t == 2) {
        if (nt > 3) asm volatile("s_waitcnt vmcnt(2)" ::: "memory");
        else asm volatile("s_waitcnt vmcnt(0)" ::: "memory");
        __syncthreads();
      }
      if (t == 3) {
        asm volatile("s_waitcnt vmcnt(0)" ::: "memory");
        __syncthreads();
      }
      u16* const Vcur = (t & 1) ? Vt0 : Vb1;
#pragma unroll
      for (int ks = 0; ks < 2; ++ks) {
        const bf16x8 af = *(const bf16x8*)(Pb + pboff[ks] + t * 64);
#pragma unroll
        for (int t2 = 0; t2 < 4; ++t2) {
          const bf16x8 bf_ = *(const bf16x8*)(Vcur + voff[ks][t2]);
          pacc[t2] = __builtin_amdgcn_mfma_f32_16x16x32_bf16(af, bf_, pacc[t2],
                                                             0, 0, 0);
        }
      }
      if (t + 2 < nt) {
        __syncthreads();
        stage_vt(t + 2, Vcur);
      }
    }
  }

#pragma unroll
  for (int t2 = 0; t2 < 4; ++t2)
#pragma unroll
    for (int r = 0; r < 4; ++r) {
      const int row = q0 + mt * 16 + lhi * 4 + r;
      const int col = h * HD + nh * 64 + t2 * 16 + l15;
      ab[(size_t)(b * SS + row) * HIDC + col] = f2bf(pacc[t2][r]);
    }
}

// ----------------------------------------------------------------------------
extern "C" void kernel_launch(void* const* d_in, const int* in_sizes, int n_in,
                              void* d_out, int out_size, void* d_ws, size_t ws_size,
                              hipStream_t stream) {
  const float* x = (const float*)d_in[0];
  const float* W_q = (const float*)d_in[1];
  const float* W_dkv = (const float*)d_in[2];
  const float* W_uk = (const float*)d_in[3];
  const float* W_uv = (const float*)d_in[4];
  const float* W_o = (const float*)d_in[5];
  const int* forget = (const int*)d_in[6];
  const int* topk = (const int*)d_in[7];
  float* out = (float*)d_out;

  char* p = (char*)d_ws;
  auto take = [&](size_t n) {
    char* r = p;
    p += (n + 255) & ~(size_t)255;
    return r;
  };

  u16* xb_hi = (u16*)take((size_t)MROWS * HIDC * 2);  // 16MB
  u16* xb_lo = (u16*)take((size_t)MROWS * HIDC * 2);  // 16MB
  u16* Wqh = (u16*)take((size_t)HIDC * HIDC * 2);     // 8MB
  u16* Wql = (u16*)take((size_t)HIDC * HIDC * 2);     // 8MB
  u16* Wdh = (u16*)take((size_t)LATC * HIDC * 2);     // 2MB
  u16* Wdl = (u16*)take((size_t)LATC * HIDC * 2);
  u16* Wukh = (u16*)take((size_t)HIDC * LATC * 2);    // 2MB
  u16* Wukl = (u16*)take((size_t)HIDC * LATC * 2);
  u16* Wuvt = (u16*)take((size_t)HIDC * LATC * 2);    // 2MB
  u16* Wot = (u16*)take((size_t)HIDC * HIDC * 2);     // 8MB
  u16* qbh = (u16*)take((size_t)MROWS * HIDC * 2);    // 16MB
  u16* qbl = (u16*)take((size_t)MROWS * HIDC * 2);    // 16MB
  u16* cbh = (u16*)take((size_t)MROWS * LATC * 2);    // 4MB
  u16* cbl = (u16*)take((size_t)MROWS * LATC * 2);    // 4MB
  u16* vt = (u16*)take((size_t)BB * HIDC * SS * 2);   // 16MB
  u16* khi = xb_hi;  // alias: xb dead after q/c GEMMs
  u16* klo = xb_lo;
  u16* ab = Wqh;     // alias: Wq dead after q-GEMM (16MB spans Wqh+Wql)

  // 1) merged prep: x split + all 5 weight transposes
  prep_all<<<dim3(19456), dim3(256), 0, stream>>>(
      x, xb_hi, xb_lo, W_q, Wqh, Wql, W_dkv, Wdh, Wdl, W_uk, Wukh, Wukl,
      W_uv, Wuvt, W_o, Wot);
  // 2) q = x @ W_q -> pre-split qbh/qbl
  gemm_split_bt<128, 3><<<dim3(MROWS / 128, HIDC / 128), 256, 0, stream>>>(
      xb_hi, xb_lo, Wqh, Wql, nullptr, qbh, qbl, MROWS, HIDC, HIDC);
  // 3) c = x @ W_dkv -> pre-split cbh/cbl (TN=64, 256 blocks)
  gemm_split_bt<64, 3><<<dim3(MROWS / 128, LATC / 64), 256, 0, stream>>>(
      xb_hi, xb_lo, Wdh, Wdl, nullptr, cbh, cbl, MROWS, LATC, HIDC);
  // 4) k = c @ W_uk -> pre-split khi/klo (aliases xb, dead now)
  gemm_split_bt<128, 3><<<dim3(MROWS / 128, HIDC / 128), 256, 0, stream>>>(
      cbh, cbl, Wukh, Wukl, nullptr, khi, klo, MROWS, HIDC, LATC);
  // 5) v^T = W_uv^T @ c_b^T, both batches in one dispatch (blockIdx.z)
  gemm_bt<2><<<dim3(HIDC / 128, SS / 128, BB), 256, 0, stream>>>(
      Wuvt, cbh, nullptr, vt, HIDC, SS, LATC,
      0, (size_t)SS * LATC, (size_t)HIDC * SS);
  // 6) attention v7 -> ab (bf16), aliases Wq (dead)
  attn_v7<<<dim3(SS / 64, NH, BB), dim3(512), 0, stream>>>(
      qbh, qbl, khi, klo, vt, forget, topk, ab);
  // 7) out = attn_out @ W_o
  gemm_bt<0><<<dim3(MROWS / 128, HIDC / 128), 256, 0, stream>>>(
      ab, Wot, out, nullptr, MROWS, HIDC, HIDC, 0, 0, 0);
}